// Round 1
// baseline (164.623 us; speedup 1.0000x reference)
//
#include <hip/hip_runtime.h>
#include <hip/hip_bf16.h>

#define NN     270
#define NFEAT  4096
#define NHID   1024
#define NHEADS 8
#define NCLS   8
#define NDRUG  175
#define NMIC   95
#define LALPHA 0.2f

typedef unsigned short u16;
typedef unsigned int   u32;
typedef __attribute__((ext_vector_type(8))) short bf16x8;
typedef __attribute__((ext_vector_type(4))) short bf16x4;
typedef __attribute__((ext_vector_type(4))) float f32x4;

static __device__ __forceinline__ u16 f2bf(float f) {
  union { float f; u32 u; } v; v.f = f;
  u32 r = v.u + 0x7FFFu + ((v.u >> 16) & 1u);   // round-to-nearest-even
  return (u16)(r >> 16);
}
static __device__ __forceinline__ float bf2f(u16 b) {
  union { u32 u; float f; } v; v.u = ((u32)b) << 16;
  return v.f;
}
static __device__ __forceinline__ float wave_red(float v) {
  #pragma unroll
  for (int o = 32; o > 0; o >>= 1) v += __shfl_down(v, o, 64);
  return v;
}

// ---------------- K0: x (f32) -> xb (bf16) ----------------
__global__ void cvt_x(const float* __restrict__ x, u16* __restrict__ xb) {
  int i = (blockIdx.x * 256 + threadIdx.x) * 8;
  if (i >= NN * NFEAT) return;
  float4 a = *(const float4*)(x + i);
  float4 b = *(const float4*)(x + i + 4);
  uint4 o;
  o.x = (u32)f2bf(a.x) | ((u32)f2bf(a.y) << 16);
  o.y = (u32)f2bf(a.z) | ((u32)f2bf(a.w) << 16);
  o.z = (u32)f2bf(b.x) | ((u32)f2bf(b.y) << 16);
  o.w = (u32)f2bf(b.z) | ((u32)f2bf(b.w) << 16);
  *(uint4*)(xb + i) = o;
}

// ---------------- K1: H = x @ W  (per head), bf16 MFMA ----------------
// One M-block of 320 (270 valid, pad rows garbage-safe: row i of C depends only
// on row i of A). BN=32 -> grid 256 blocks = 256 CUs; W streamed exactly once.
__global__ __launch_bounds__(512) void gemm1(const u16* __restrict__ xb,
                                             const float* __restrict__ W,
                                             float* __restrict__ H,
                                             u16* __restrict__ Hb) {
  __shared__ __align__(16) u16 lA[320 * 72];  // [row][k], stride 72 (pad: align+bank)
  __shared__ __align__(16) u16 lB[32 * 72];   // [col][k] transposed, k contiguous
  const int tid  = threadIdx.x;
  const int lane = tid & 63;
  const int wid  = tid >> 6;
  const int wm   = wid >> 1;       // 0..3 : 80-row band
  const int wn   = wid & 1;        // 0..1 : 16-col band
  const int c0   = blockIdx.x * 32;
  const int headB = c0 >> 10;
  const int jB    = c0 & 1023;
  f32x4 acc[5];
  #pragma unroll
  for (int m = 0; m < 5; ++m) acc[m] = (f32x4){0.f, 0.f, 0.f, 0.f};

  for (int k0 = 0; k0 < NFEAT; k0 += 64) {
    __syncthreads();
    // stage A: 320x64 bf16 (2560 8-elem chunks / 512 thr = 5 each)
    #pragma unroll
    for (int it = 0; it < 5; ++it) {
      int f   = tid + it * 512;
      int row = f >> 3;
      int kc  = (f & 7) << 3;
      bf16x8 v = {0,0,0,0,0,0,0,0};
      if (row < NN) v = *(const bf16x8*)(xb + (size_t)row * NFEAT + k0 + kc);
      *(bf16x8*)(lA + row * 72 + kc) = v;
    }
    // stage B: 64 k-rows x 32 cols of W (f32 -> bf16, transpose into [col][k])
    {
      int kk = tid >> 3;          // 0..63
      int jc = (tid & 7) << 2;    // 0,4,..,28
      const float4 wv = *(const float4*)(W + (size_t)headB * NFEAT * NHID
                                           + (size_t)(k0 + kk) * NHID + jB + jc);
      lB[(jc + 0) * 72 + kk] = f2bf(wv.x);
      lB[(jc + 1) * 72 + kk] = f2bf(wv.y);
      lB[(jc + 2) * 72 + kk] = f2bf(wv.z);
      lB[(jc + 3) * 72 + kk] = f2bf(wv.w);
    }
    __syncthreads();
    #pragma unroll
    for (int sub = 0; sub < 2; ++sub) {
      int ks = sub * 32 + ((lane >> 4) << 3);     // lane's 8 contiguous k
      bf16x8 bfrag = *(const bf16x8*)(lB + (wn * 16 + (lane & 15)) * 72 + ks);
      #pragma unroll
      for (int m = 0; m < 5; ++m) {
        int row = wm * 80 + m * 16 + (lane & 15);
        bf16x8 afrag = *(const bf16x8*)(lA + row * 72 + ks);
        acc[m] = __builtin_amdgcn_mfma_f32_16x16x32_bf16(afrag, bfrag, acc[m], 0, 0, 0);
      }
    }
  }
  const int c    = c0 + wn * 16 + (lane & 15);
  const int head = c >> 10;
  const int j    = c & 1023;
  #pragma unroll
  for (int m = 0; m < 5; ++m) {
    #pragma unroll
    for (int r = 0; r < 4; ++r) {
      int row = wm * 80 + m * 16 + ((lane >> 4) << 2) + r;
      if (row < NN) {
        float v = acc[m][r];
        size_t off = (size_t)head * NN * NHID + (size_t)row * NHID + j;
        H[off]  = v;
        Hb[off] = f2bf(v);
      }
    }
  }
}

// ---------------- K2: src/dst = H @ a_src / a_dst ----------------
__global__ void srcdst(const float* __restrict__ H, const float* __restrict__ a_src,
                       const float* __restrict__ a_dst, float* __restrict__ srcv,
                       float* __restrict__ dstv) {
  const int i = blockIdx.x, h = blockIdx.y;
  const float* hr = H + ((size_t)h * NN + i) * NHID;
  const float* as = a_src + h * NHID;
  const float* ad = a_dst + h * NHID;
  float s = 0.f, d = 0.f;
  for (int j = threadIdx.x; j < NHID; j += 256) {
    float v = hr[j];
    s += v * as[j];
    d += v * ad[j];
  }
  s = wave_red(s); d = wave_red(d);
  __shared__ float rb[8];
  const int lane = threadIdx.x & 63, wid = threadIdx.x >> 6;
  if (lane == 0) { rb[wid] = s; rb[4 + wid] = d; }
  __syncthreads();
  if (threadIdx.x == 0) {
    srcv[h * NN + i] = rb[0] + rb[1] + rb[2] + rb[3];
    dstv[h * NN + i] = rb[4] + rb[5] + rb[6] + rb[7];
  }
}

// ---------------- K3a: e = exp(-leakyrelu(src_i+dst_j))*mask, rowsum ----------------
// e stored bf16 with K padded to 320 (zeros) for the aggregation MFMA.
__global__ void ekern(const int* __restrict__ adj, const float* __restrict__ srcv,
                      const float* __restrict__ dstv, u16* __restrict__ eb,
                      float* __restrict__ rowsum) {
  const int i = blockIdx.x, h = blockIdx.y;
  const int n = threadIdx.x;          // 0..319
  float ev = 0.f;
  if (n < NN && adj[i * NN + n] != 0) {
    float lg = srcv[h * NN + i] + dstv[h * NN + n];
    float lr = lg > 0.f ? lg : LALPHA * lg;
    ev = expf(-lr);
  }
  u16 evb = f2bf(ev);
  eb[(size_t)h * NN * 320 + (size_t)i * 320 + n] = evb;
  float evr = wave_red(bf2f(evb));    // sum the bf16-rounded weights (consistency)
  __shared__ float rb[5];
  const int lane = threadIdx.x & 63, wid = threadIdx.x >> 6;
  if (lane == 0) rb[wid] = evr;
  __syncthreads();
  if (threadIdx.x == 0) rowsum[h * NN + i] = rb[0] + rb[1] + rb[2] + rb[3] + rb[4];
}

// ---------------- K3b: h2 = elu((e @ H) / rowsum), concat heads ----------------
__global__ __launch_bounds__(512) void gemm2(const u16* __restrict__ eb,
                                             const u16* __restrict__ Hb,
                                             const float* __restrict__ rowsum,
                                             float* __restrict__ h2) {
  __shared__ __align__(16) u16 lA[320 * 72];
  __shared__ __align__(16) u16 lB[32 * 72];
  const int tid  = threadIdx.x;
  const int lane = tid & 63;
  const int wid  = tid >> 6;
  const int wm   = wid >> 1;
  const int wn   = wid & 1;
  const int head = blockIdx.x >> 5;
  const int j0   = (blockIdx.x & 31) * 32;
  f32x4 acc[5];
  #pragma unroll
  for (int m = 0; m < 5; ++m) acc[m] = (f32x4){0.f, 0.f, 0.f, 0.f};

  for (int k0 = 0; k0 < 320; k0 += 64) {
    __syncthreads();
    #pragma unroll
    for (int it = 0; it < 5; ++it) {
      int f   = tid + it * 512;
      int row = f >> 3;
      int kc  = (f & 7) << 3;
      bf16x8 v = {0,0,0,0,0,0,0,0};
      if (row < NN) v = *(const bf16x8*)(eb + (size_t)head * NN * 320 + (size_t)row * 320 + k0 + kc);
      *(bf16x8*)(lA + row * 72 + kc) = v;
    }
    {
      int kk = tid >> 3;
      int jc = (tid & 7) << 2;
      int k  = k0 + kk;
      u16 v0 = 0, v1 = 0, v2 = 0, v3 = 0;
      if (k < NN) {
        bf16x4 hv = *(const bf16x4*)(Hb + (size_t)head * NN * NHID + (size_t)k * NHID + j0 + jc);
        v0 = (u16)hv[0]; v1 = (u16)hv[1]; v2 = (u16)hv[2]; v3 = (u16)hv[3];
      }
      lB[(jc + 0) * 72 + kk] = v0;
      lB[(jc + 1) * 72 + kk] = v1;
      lB[(jc + 2) * 72 + kk] = v2;
      lB[(jc + 3) * 72 + kk] = v3;
    }
    __syncthreads();
    #pragma unroll
    for (int sub = 0; sub < 2; ++sub) {
      int ks = sub * 32 + ((lane >> 4) << 3);
      bf16x8 bfrag = *(const bf16x8*)(lB + (wn * 16 + (lane & 15)) * 72 + ks);
      #pragma unroll
      for (int m = 0; m < 5; ++m) {
        int row = wm * 80 + m * 16 + (lane & 15);
        bf16x8 afrag = *(const bf16x8*)(lA + row * 72 + ks);
        acc[m] = __builtin_amdgcn_mfma_f32_16x16x32_bf16(afrag, bfrag, acc[m], 0, 0, 0);
      }
    }
  }
  const int jj = j0 + wn * 16 + (lane & 15);
  #pragma unroll
  for (int m = 0; m < 5; ++m) {
    #pragma unroll
    for (int r = 0; r < 4; ++r) {
      int row = wm * 80 + m * 16 + ((lane >> 4) << 2) + r;
      if (row < NN) {
        float v = acc[m][r] / rowsum[head * NN + row];
        v = v > 0.f ? v : expm1f(v);                 // elu
        h2[(size_t)row * (NHEADS * NHID) + head * NHID + jj] = v;
      }
    }
  }
}

// ---------------- K4: layer-2 h = h2 @ W_out, plus src2/dst2 ----------------
__global__ void layer2(const float* __restrict__ h2, const float* __restrict__ Wout,
                       const float* __restrict__ aos, const float* __restrict__ aod,
                       float* __restrict__ hL2, float* __restrict__ src2,
                       float* __restrict__ dst2) {
  const int i = blockIdx.x;
  float acc[8] = {0,0,0,0,0,0,0,0};
  for (int k = threadIdx.x; k < NHEADS * NHID; k += 256) {
    float hv = h2[(size_t)i * (NHEADS * NHID) + k];
    const float4 w0 = *(const float4*)(Wout + (size_t)k * 8);
    const float4 w1 = *(const float4*)(Wout + (size_t)k * 8 + 4);
    acc[0] += hv * w0.x; acc[1] += hv * w0.y; acc[2] += hv * w0.z; acc[3] += hv * w0.w;
    acc[4] += hv * w1.x; acc[5] += hv * w1.y; acc[6] += hv * w1.z; acc[7] += hv * w1.w;
  }
  #pragma unroll
  for (int c = 0; c < 8; ++c) acc[c] = wave_red(acc[c]);
  __shared__ float rb[4][8];
  const int lane = threadIdx.x & 63, wid = threadIdx.x >> 6;
  if (lane == 0) {
    #pragma unroll
    for (int c = 0; c < 8; ++c) rb[wid][c] = acc[c];
  }
  __syncthreads();
  if (threadIdx.x == 0) {
    float s = 0.f, d = 0.f;
    #pragma unroll
    for (int c = 0; c < 8; ++c) {
      float v = rb[0][c] + rb[1][c] + rb[2][c] + rb[3][c];
      hL2[i * 8 + c] = v;
      s += v * aos[c];
      d += v * aod[c];
    }
    src2[i] = s; dst2[i] = d;
  }
}

// ---------------- K5a: layer-2 attention + aggregation + elu ----------------
__global__ void out2k(const int* __restrict__ adj, const float* __restrict__ src2,
                      const float* __restrict__ dst2, const float* __restrict__ hL2,
                      float* __restrict__ out2) {
  const int i = blockIdx.x;
  float se = 0.f, acc[8] = {0,0,0,0,0,0,0,0};
  for (int n = threadIdx.x; n < NN; n += 256) {
    if (adj[i * NN + n] != 0) {
      float lg = src2[i] + dst2[n];
      float lr = lg > 0.f ? lg : LALPHA * lg;
      float ev = expf(-lr);
      se += ev;
      #pragma unroll
      for (int c = 0; c < 8; ++c) acc[c] += ev * hL2[n * 8 + c];
    }
  }
  se = wave_red(se);
  #pragma unroll
  for (int c = 0; c < 8; ++c) acc[c] = wave_red(acc[c]);
  __shared__ float rb[4][9];
  const int lane = threadIdx.x & 63, wid = threadIdx.x >> 6;
  if (lane == 0) {
    #pragma unroll
    for (int c = 0; c < 8; ++c) rb[wid][c] = acc[c];
    rb[wid][8] = se;
  }
  __syncthreads();
  if (threadIdx.x == 0) {
    float s = rb[0][8] + rb[1][8] + rb[2][8] + rb[3][8];
    #pragma unroll
    for (int c = 0; c < 8; ++c) {
      float v = (rb[0][c] + rb[1][c] + rb[2][c] + rb[3][c]) / s;
      out2[i * 8 + c] = v > 0.f ? v : expm1f(v);
    }
  }
}

// ---------------- K5b: out = drug @ alpha1 @ mic^T ----------------
__global__ void finalk(const float* __restrict__ out2, const float* __restrict__ alpha1,
                       float* __restrict__ out) {
  int t = blockIdx.x * 256 + threadIdx.x;
  if (t >= NDRUG * NMIC) return;
  int d = t / NMIC, m = t % NMIC;
  const float* dr = out2 + d * 8;
  const float* mi = out2 + (NDRUG + m) * 8;
  float r = 0.f;
  #pragma unroll
  for (int c2 = 0; c2 < 8; ++c2) {
    float a = 0.f;
    #pragma unroll
    for (int c1 = 0; c1 < 8; ++c1) a += dr[c1] * alpha1[c1 * 8 + c2];
    r += a * mi[c2];
  }
  out[t] = r;
}

extern "C" void kernel_launch(void* const* d_in, const int* in_sizes, int n_in,
                              void* d_out, int out_size, void* d_ws, size_t ws_size,
                              hipStream_t stream) {
  const float* x      = (const float*)d_in[0];
  const int*   adj    = (const int*)d_in[1];
  const float* W      = (const float*)d_in[2];
  const float* a_src  = (const float*)d_in[3];
  const float* a_dst  = (const float*)d_in[4];
  const float* W_out  = (const float*)d_in[5];
  const float* aos    = (const float*)d_in[6];
  const float* aod    = (const float*)d_in[7];
  const float* alpha1 = (const float*)d_in[8];
  float* out = (float*)d_out;

  char* p = (char*)d_ws;
  auto take = [&](size_t bytes) {
    char* q = p;
    p += (bytes + 255) & ~(size_t)255;
    return q;
  };
  u16*   xb   = (u16*)  take((size_t)NN * NFEAT * 2);
  float* H    = (float*)take((size_t)NHEADS * NN * NHID * 4);
  u16*   Hb   = (u16*)  take((size_t)NHEADS * NN * NHID * 2);
  float* srcv = (float*)take((size_t)NHEADS * NN * 4);
  float* dstv = (float*)take((size_t)NHEADS * NN * 4);
  u16*   eb   = (u16*)  take((size_t)NHEADS * NN * 320 * 2);
  float* rs   = (float*)take((size_t)NHEADS * NN * 4);
  float* h2   = (float*)take((size_t)NN * NHEADS * NHID * 4);
  float* hL2  = (float*)take((size_t)NN * NCLS * 4);
  float* s2   = (float*)take((size_t)NN * 4);
  float* d2   = (float*)take((size_t)NN * 4);
  float* o2   = (float*)take((size_t)NN * NCLS * 4);

  cvt_x<<<540, 256, 0, stream>>>(x, xb);
  gemm1<<<256, 512, 0, stream>>>(xb, W, H, Hb);
  srcdst<<<dim3(NN, NHEADS), 256, 0, stream>>>(H, a_src, a_dst, srcv, dstv);
  ekern<<<dim3(NN, NHEADS), 320, 0, stream>>>(adj, srcv, dstv, eb, rs);
  gemm2<<<256, 512, 0, stream>>>(eb, Hb, rs, h2);
  layer2<<<NN, 256, 0, stream>>>(h2, W_out, aos, aod, hL2, s2, d2);
  out2k<<<NN, 256, 0, stream>>>(adj, s2, d2, hL2, o2);
  finalk<<<65, 256, 0, stream>>>(o2, alpha1, out);
}